// Round 5
// baseline (105.718 us; speedup 1.0000x reference)
//
#include <hip/hip_runtime.h>
#include <hip/hip_bf16.h>

typedef __attribute__((ext_vector_type(4))) float  float4v;
typedef __attribute__((ext_vector_type(4))) short  short4v;
typedef __attribute__((ext_vector_type(8))) short  short8v;
typedef __attribute__((ext_vector_type(4))) float  f32x4;

// f32 -> bf16 RTNE via HW cvt (compiler emits v_cvt_pk_bf16_f32)
__device__ __forceinline__ short f2bf(float f) {
  __hip_bfloat16 h = __float2bfloat16(f);
  return *reinterpret_cast<short*>(&h);
}

__device__ __forceinline__ short8v cvt8(float4v v0, float4v v1) {
  short8v s;
  s[0]=f2bf(v0[0]); s[1]=f2bf(v0[1]); s[2]=f2bf(v0[2]); s[3]=f2bf(v0[3]);
  s[4]=f2bf(v1[0]); s[5]=f2bf(v1[1]); s[6]=f2bf(v1[2]); s[7]=f2bf(v1[3]);
  return s;
}

// XOR swizzle for LDS bf16 tiles: short idx k ^= ((row&7)<<3)
__device__ __forceinline__ int swz(int row, int k, int ld) {
  return row * ld + (k ^ ((row & 7) << 3));
}

// async global->LDS, 16B per lane; LDS dest = wave-uniform base + lane*16
__device__ __forceinline__ void gll16(const void* g, void* l) {
  __builtin_amdgcn_global_load_lds(
      (const __attribute__((address_space(1))) unsigned int*)g,
      (__attribute__((address_space(3))) unsigned int*)l, 16, 0, 0);
}

#define SB() __builtin_amdgcn_sched_barrier(0)
#define WAIT16() asm volatile("s_waitcnt vmcnt(16)" ::: "memory")

// -------------------------------------------------------------------------
// Kernel 0: wt[f][d] = bf16(W[d][f])  (one-time 128x128 transpose+convert)
// -------------------------------------------------------------------------
__global__ __launch_bounds__(256) void k0_wt(const float* __restrict__ W,
                                             short* __restrict__ wt) {
  const int task = blockIdx.x * 256 + threadIdx.x;   // 2048 tasks
  const int f = task & 127;
  const int dc = (task >> 7) * 8;
  short8v s;
#pragma unroll
  for (int j = 0; j < 8; ++j) s[j] = f2bf(W[(size_t)(dc + j) * 128 + f]);
  *(short8v*)(wt + (size_t)f * 128 + dc) = s;
}

// -------------------------------------------------------------------------
// Kernel 1: ht[b][f][m] = bf16( sum_d feat[b][m][d] * W[d][f] )   (H^T)
// grid (N/64, B), 256 thr. No LDS, no barrier: 4 independent waves; A-frags
// direct from feat (contiguous/lane); B-frags direct from wt (32 KB = L1).
// -------------------------------------------------------------------------
__global__ __launch_bounds__(256) void k1_feat_x_w(
    const float* __restrict__ feat, const short* __restrict__ wt,
    short* __restrict__ ht, int N) {
  const int t = threadIdx.x;
  const int batch = blockIdx.y;
  const int m0 = blockIdx.x * 64;
  const int lane = t & 63, wid = t >> 6;
  const int lr = lane & 15, lk = (lane >> 4) * 8;
  const float* pa = feat + (size_t)batch * N * 128
                  + (size_t)(m0 + wid * 16 + lr) * 128 + lk;

  f32x4 acc[8];
#pragma unroll
  for (int j = 0; j < 8; ++j) acc[j] = (f32x4){0.f, 0.f, 0.f, 0.f};

#pragma unroll
  for (int kk = 0; kk < 4; ++kk) {
    float4v v0 = ((const float4v*)(pa + kk * 32))[0];
    float4v v1 = ((const float4v*)(pa + kk * 32))[1];
    short8v a = cvt8(v0, v1);
#pragma unroll
    for (int ni = 0; ni < 8; ++ni) {
      short8v b = *(const short8v*)(wt + (size_t)(ni * 16 + lr) * 128 + kk * 32 + lk);
      acc[ni] = __builtin_amdgcn_mfma_f32_16x16x32_bf16(a, b, acc[ni], 0, 0, 0);
    }
  }

  // store ht[b][f][m]; D-frag: col(f)=lane&15, row(m)=(lane>>4)*4+r
  short* hb = ht + (size_t)batch * 128 * N;
  const int m = m0 + wid * 16 + (lane >> 4) * 4;
#pragma unroll
  for (int ni = 0; ni < 8; ++ni) {
    const int f = ni * 16 + lr;
    short4v s;
#pragma unroll
    for (int r = 0; r < 4; ++r) s[r] = f2bf(acc[ni][r]);
    *(short4v*)(hb + (size_t)f * N + m) = s;
  }
}

// -------------------------------------------------------------------------
// Kernel 2: out[b][m][f] = relu( sum_k A[b][m][k] * H[k][f] + bias[f] )
// grid (N/32, B) = 512 blocks (2/CU), 128 thr = 2 waves.
// WAVE-PRIVATE pipeline, ZERO barriers: each wave owns 32 m-rows x 64 f
// (wave id = f-half) and stages its own H slice to its own LDS region via
// global_load_lds; A fragments load straight to registers. Double-buffered;
// completion enforced by counted `s_waitcnt vmcnt(16)` (8 gll + 8 A-loads
// per step, oldest-first drain) + sched_barrier fences. No vmcnt(0) drain
// anywhere in the loop -> HBM stays saturated.
// -------------------------------------------------------------------------
__global__ __launch_bounds__(128, 1) void k2_a_x_h(
    const float* __restrict__ A, const short* __restrict__ ht,
    const float* __restrict__ bias, float* __restrict__ out, int N) {
  __shared__ __align__(16) short Hs[2][2][64 * 64];   // [wave][buf] 32 KB
  const int t = threadIdx.x;
  const int lane = t & 63, fh = t >> 6;   // wave id = f-half (0/1)

  // XCD-chunked swizzle: each XCD gets a contiguous run of m-tiles of one
  // batch -> that batch's H stays resident in the XCD's L2 (~1 MB).
  const int nwg = gridDim.x * gridDim.y;
  int wg = blockIdx.x + gridDim.x * blockIdx.y;
  if ((nwg & 7) == 0) wg = (wg & 7) * (nwg >> 3) + (wg >> 3);
  const int mtiles = gridDim.x;
  const int batch = wg / mtiles;
  const int m0 = (wg - batch * mtiles) * 32;

  const float* Ab = A + (size_t)batch * N * N;
  const short* hb = ht + (size_t)batch * 128 * N + (size_t)fh * 64 * N;

  const int lr = lane & 15, lk = (lane >> 4) * 8;
  const int hf = lane >> 3, hks = (lane & 7) * 8;   // H stage lane map

  short* H0 = &Hs[fh][0][0];
  short* H1 = &Hs[fh][1][0];

  // stage this wave's 64f x 64k H tile: 8 x gll16 (1 KB each), source
  // pre-swizzled so the linear LDS write lands in swz() layout
  auto stageH = [&](int k0, short* dst) {
#pragma unroll
    for (int i = 0; i < 8; ++i) {
      const int f8 = i * 8;
      const short* g = hb + (size_t)(f8 + hf) * N + k0 + (hks ^ (hf << 3));
      gll16(g, dst + f8 * 64);
    }
  };
  // A fragments for 2 m-frags x 2 k-halves: 8 dwordx4 to regs
  auto loadA = [&](int k0, float4v (&ar)[8]) {
    const float* p0 = Ab + (size_t)(m0 + lr) * N + k0 + lk;
    const float* p1 = p0 + (size_t)16 * N;
    ar[0] = ((const float4v*)p0)[0];          ar[1] = ((const float4v*)p0)[1];
    ar[2] = ((const float4v*)(p0 + 32))[0];   ar[3] = ((const float4v*)(p0 + 32))[1];
    ar[4] = ((const float4v*)p1)[0];          ar[5] = ((const float4v*)p1)[1];
    ar[6] = ((const float4v*)(p1 + 32))[0];   ar[7] = ((const float4v*)(p1 + 32))[1];
  };

  f32x4 acc[2][4];
#pragma unroll
  for (int i = 0; i < 2; ++i)
#pragma unroll
    for (int j = 0; j < 4; ++j) acc[i][j] = (f32x4){0.f, 0.f, 0.f, 0.f};

  auto compute = [&](const short* Hbuf, float4v (&ar)[8]) {
    short8v a[2][2];
    a[0][0] = cvt8(ar[0], ar[1]);  a[0][1] = cvt8(ar[2], ar[3]);
    a[1][0] = cvt8(ar[4], ar[5]);  a[1][1] = cvt8(ar[6], ar[7]);
#pragma unroll
    for (int kk = 0; kk < 2; ++kk)
#pragma unroll
      for (int ni = 0; ni < 4; ++ni) {
        short8v b = *(const short8v*)(Hbuf + swz(ni * 16 + lr, kk * 32 + lk, 64));
#pragma unroll
        for (int mi = 0; mi < 2; ++mi)
          acc[mi][ni] = __builtin_amdgcn_mfma_f32_16x16x32_bf16(a[mi][kk], b, acc[mi][ni], 0, 0, 0);
      }
  };

  float4v arA[8], arB[8];   // static register double-buffer (rule #20)
  const int NT = N / 64;    // 64 steps (even)

  stageH(0, H0);
  loadA(0, arA);
  for (int tt = 0; tt < NT; tt += 2) {
    const int kn = (tt + 1) * 64;
    stageH(kn, H1);
    loadA(kn, arB);
    SB(); WAIT16(); SB();        // step tt's 16 vmem ops provably complete
    compute(H0, arA);
    const int kn2 = (tt + 2 < NT) ? (tt + 2) * 64 : (NT - 1) * 64;  // tail: dummy
    stageH(kn2, H0);
    loadA(kn2, arA);
    SB(); WAIT16(); SB();        // step tt+1 complete
    compute(H1, arB);
  }

  // epilogue: bias + relu; D-frag: col(f)=lane&15, row(m)=(lane>>4)*4+r
  float* ob = out + (size_t)batch * N * 128 + fh * 64;
#pragma unroll
  for (int ni = 0; ni < 4; ++ni) {
    const int fl = ni * 16 + lr;
    const float bv = bias[fh * 64 + fl];
#pragma unroll
    for (int mi = 0; mi < 2; ++mi) {
      const int mbase = m0 + mi * 16 + (lane >> 4) * 4;
#pragma unroll
      for (int r = 0; r < 4; ++r)
        ob[(size_t)(mbase + r) * 128 + fl] = fmaxf(acc[mi][ni][r] + bv, 0.f);
    }
  }
}

extern "C" void kernel_launch(void* const* d_in, const int* in_sizes, int n_in,
                              void* d_out, int out_size, void* d_ws, size_t ws_size,
                              hipStream_t stream) {
  const float* feat = (const float*)d_in[0];  // [B,N,128]
  const float* A    = (const float*)d_in[1];  // [B,N,N]
  const float* W    = (const float*)d_in[2];  // [128,128]
  const float* bias = (const float*)d_in[3];  // [128]
  float* out = (float*)d_out;                 // [B,N,128]

  const int featN = in_sizes[0];      // B*N*128
  const int aN    = in_sizes[1];      // B*N*N
  const int BN    = featN / 128;      // B*N
  const int N     = aN / BN;
  const int Bb    = BN / N;

  short* wt = (short*)d_ws;           // [128][128] bf16 (32 KB)
  short* ht = wt + 128 * 128;         // [B][128][N] bf16

  hipLaunchKernelGGL(k0_wt, dim3(8), dim3(256), 0, stream, W, wt);
  hipLaunchKernelGGL(k1_feat_x_w, dim3(N / 64, Bb), dim3(256), 0, stream, feat, wt, ht, N);
  hipLaunchKernelGGL(k2_a_x_h, dim3(N / 32, Bb), dim3(128), 0, stream, A, ht, bias, out, N);
}

// Round 6
// 91.682 us; speedup vs baseline: 1.1531x; 1.1531x over previous
//
#include <hip/hip_runtime.h>
#include <hip/hip_bf16.h>

typedef __attribute__((ext_vector_type(4))) float  float4v;
typedef __attribute__((ext_vector_type(4))) short  short4v;
typedef __attribute__((ext_vector_type(8))) short  short8v;
typedef __attribute__((ext_vector_type(4))) float  f32x4;

// f32 -> bf16 RTNE via HW cvt (compiler emits v_cvt_pk_bf16_f32)
__device__ __forceinline__ short f2bf(float f) {
  __hip_bfloat16 h = __float2bfloat16(f);
  return *reinterpret_cast<short*>(&h);
}

__device__ __forceinline__ short8v cvt8(float4v v0, float4v v1) {
  short8v s;
  s[0]=f2bf(v0[0]); s[1]=f2bf(v0[1]); s[2]=f2bf(v0[2]); s[3]=f2bf(v0[3]);
  s[4]=f2bf(v1[0]); s[5]=f2bf(v1[1]); s[6]=f2bf(v1[2]); s[7]=f2bf(v1[3]);
  return s;
}

// XOR swizzle for LDS bf16 tiles: short idx k ^= ((row&7)<<3)
__device__ __forceinline__ int swz(int row, int k, int ld) {
  return row * ld + (k ^ ((row & 7) << 3));
}

// async global->LDS, 16B per lane; LDS dest = wave-uniform base + lane*16
__device__ __forceinline__ void gll16(const void* g, void* l) {
  __builtin_amdgcn_global_load_lds(
      (const __attribute__((address_space(1))) unsigned int*)g,
      (__attribute__((address_space(3))) unsigned int*)l, 16, 0, 0);
}

// -------------------------------------------------------------------------
// Kernel 0: wt[f][d] = bf16(W[d][f])  (one-time 128x128 transpose+convert)
// -------------------------------------------------------------------------
__global__ __launch_bounds__(256) void k0_wt(const float* __restrict__ W,
                                             short* __restrict__ wt) {
  const int task = blockIdx.x * 256 + threadIdx.x;   // 2048 tasks
  const int f = task & 127;
  const int dc = (task >> 7) * 8;
  short8v s;
#pragma unroll
  for (int j = 0; j < 8; ++j) s[j] = f2bf(W[(size_t)(dc + j) * 128 + f]);
  *(short8v*)(wt + (size_t)f * 128 + dc) = s;
}

// -------------------------------------------------------------------------
// Kernel 1: ht[b][f][m] = bf16( sum_d feat[b][m][d] * W[d][f] )   (H^T)
// grid (N/64, B), 256 thr. No LDS, no barrier: 4 independent waves; A-frags
// direct from feat (contiguous/lane); B-frags direct from wt (32 KB = L1).
// -------------------------------------------------------------------------
__global__ __launch_bounds__(256) void k1_feat_x_w(
    const float* __restrict__ feat, const short* __restrict__ wt,
    short* __restrict__ ht, int N) {
  const int t = threadIdx.x;
  const int batch = blockIdx.y;
  const int m0 = blockIdx.x * 64;
  const int lane = t & 63, wid = t >> 6;
  const int lr = lane & 15, lk = (lane >> 4) * 8;
  const float* pa = feat + (size_t)batch * N * 128
                  + (size_t)(m0 + wid * 16 + lr) * 128 + lk;

  f32x4 acc[8];
#pragma unroll
  for (int j = 0; j < 8; ++j) acc[j] = (f32x4){0.f, 0.f, 0.f, 0.f};

#pragma unroll
  for (int kk = 0; kk < 4; ++kk) {
    float4v v0 = ((const float4v*)(pa + kk * 32))[0];
    float4v v1 = ((const float4v*)(pa + kk * 32))[1];
    short8v a = cvt8(v0, v1);
#pragma unroll
    for (int ni = 0; ni < 8; ++ni) {
      short8v b = *(const short8v*)(wt + (size_t)(ni * 16 + lr) * 128 + kk * 32 + lk);
      acc[ni] = __builtin_amdgcn_mfma_f32_16x16x32_bf16(a, b, acc[ni], 0, 0, 0);
    }
  }

  // store ht[b][f][m]; D-frag: col(f)=lane&15, row(m)=(lane>>4)*4+r
  short* hb = ht + (size_t)batch * 128 * N;
  const int m = m0 + wid * 16 + (lane >> 4) * 4;
#pragma unroll
  for (int ni = 0; ni < 8; ++ni) {
    const int f = ni * 16 + lr;
    short4v s;
#pragma unroll
    for (int r = 0; r < 4; ++r) s[r] = f2bf(acc[ni][r]);
    *(short4v*)(hb + (size_t)f * N + m) = s;
  }
}

// -------------------------------------------------------------------------
// Kernel 2: out[b][m][f] = relu( sum_k A[b][m][k] * H[k][f] + bias[f] )
// grid (N/64, B) = 256 blocks (1/CU), 256 thr = 4 waves.
// Tile 64m x 128f, BK=64. Waves split by m (16 rows each) -> A is
// WAVE-PRIVATE: global -> regs -> cvt -> MFMA (reg double-buffer, depth 2).
// H is shared: gll16 into TRIPLE-buffered LDS, depth-2 prefetch.
// Sync = raw s_barrier preceded by counted `s_waitcnt vmcnt(12)`:
// per step each wave issues 4 gll (mid-body) + 4 A-loads (body end), so at
// body(t) top the ops newer than G(t) are exactly A(t)+G(t+1)+A(t+1) = 12.
// The pipeline NEVER drains below 12 in-flight vmem ops -> no vmcnt(0)
// stall anywhere in the main loop.
// -------------------------------------------------------------------------
__global__ __launch_bounds__(256, 1) void k2_a_x_h(
    const float* __restrict__ A, const short* __restrict__ ht,
    const float* __restrict__ bias, float* __restrict__ out, int N) {
  __shared__ __align__(16) short Hs[3][128 * 64];   // 48 KB
  const int t = threadIdx.x;
  const int lane = t & 63, wid = t >> 6;

  // XCD-chunked swizzle (nwg = 256, multiple of 8 -> bijective)
  const int nwg = gridDim.x * gridDim.y;
  int wg = blockIdx.x + gridDim.x * blockIdx.y;
  if ((nwg & 7) == 0) wg = (wg & 7) * (nwg >> 3) + (wg >> 3);
  const int mtiles = gridDim.x;
  const int batch = wg / mtiles;
  const int m0 = (wg - batch * mtiles) * 64;

  const float* Ab = A + (size_t)batch * N * N;
  const short* hb = ht + (size_t)batch * 128 * N;

  const int lr = lane & 15, lk = (lane >> 4) * 8;
  const int hf = lane >> 3, hks = (lane & 7) * 8;   // H stage lane map

  const float* pa = Ab + (size_t)(m0 + wid * 16 + lr) * N + lk;

  // stage 32 f-rows of H (wave's share of the 128-row tile): 4 gll x 1 KB,
  // source pre-swizzled so the linear LDS write lands in swz() layout
  auto stageH = [&](int k0, short* dst) {
#pragma unroll
    for (int i = 0; i < 4; ++i) {
      const int f8 = (wid * 4 + i) * 8;
      const short* g = hb + (size_t)(f8 + hf) * N + k0 + (hks ^ (hf << 3));
      gll16(g, dst + f8 * 64);
    }
  };
  // wave-private A fragments: 16 rows x 64 k -> 4 dwordx4 per lane
  auto loadA = [&](int k0, float4v (&ar)[4]) {
    const float* p = pa + k0;
    ar[0] = ((const float4v*)p)[0];
    ar[1] = ((const float4v*)p)[1];
    ar[2] = ((const float4v*)(p + 32))[0];
    ar[3] = ((const float4v*)(p + 32))[1];
  };

  f32x4 acc[8];
#pragma unroll
  for (int j = 0; j < 8; ++j) acc[j] = (f32x4){0.f, 0.f, 0.f, 0.f};

  auto compute = [&](const short* Hbuf, float4v (&ar)[4]) {
    short8v a0 = cvt8(ar[0], ar[1]);
    short8v a1 = cvt8(ar[2], ar[3]);
#pragma unroll
    for (int ni = 0; ni < 8; ++ni) {
      short8v b = *(const short8v*)(Hbuf + swz(ni * 16 + lr, lk, 64));
      acc[ni] = __builtin_amdgcn_mfma_f32_16x16x32_bf16(a0, b, acc[ni], 0, 0, 0);
    }
#pragma unroll
    for (int ni = 0; ni < 8; ++ni) {
      short8v b = *(const short8v*)(Hbuf + swz(ni * 16 + lr, 32 + lk, 64));
      acc[ni] = __builtin_amdgcn_mfma_f32_16x16x32_bf16(a1, b, acc[ni], 0, 0, 0);
    }
  };

  float4v arE[4], arO[4];   // static reg double-buffer (rule #20)
  const int NT = N / 64;    // 64 (even)

  // prologue: G(0), A(0), G(1), A(1)  -- matches steady-state issue order
  stageH(0, &Hs[0][0]);
  loadA(0, arE);
  stageH(64, &Hs[1][0]);
  loadA(64, arO);

#define K2_BODY(T_, AR_)                                                     \
  {                                                                          \
    const int t_ = (T_);                                                     \
    if (t_ == NT - 1) { asm volatile("s_waitcnt vmcnt(4)" ::: "memory"); }   \
    else              { asm volatile("s_waitcnt vmcnt(12)" ::: "memory"); }  \
    __builtin_amdgcn_s_barrier();                                            \
    if (t_ + 2 < NT) stageH((t_ + 2) * 64, &Hs[(t_ + 2) % 3][0]);            \
    compute(&Hs[t_ % 3][0], AR_);                                            \
    if (t_ + 2 < NT) loadA((t_ + 2) * 64, AR_);                              \
  }

  for (int tt = 0; tt < NT; tt += 2) {
    K2_BODY(tt, arE);
    K2_BODY(tt + 1, arO);
  }
#undef K2_BODY

  // epilogue: bias + relu; D-frag: col(f)=lane&15, row(m)=(lane>>4)*4+r
  float* ob = out + (size_t)batch * N * 128;
#pragma unroll
  for (int ni = 0; ni < 8; ++ni) {
    const int f = ni * 16 + lr;
    const float bv = bias[f];
    const int mbase = m0 + wid * 16 + (lane >> 4) * 4;
#pragma unroll
    for (int r = 0; r < 4; ++r)
      ob[(size_t)(mbase + r) * 128 + f] = fmaxf(acc[ni][r] + bv, 0.f);
  }
}

extern "C" void kernel_launch(void* const* d_in, const int* in_sizes, int n_in,
                              void* d_out, int out_size, void* d_ws, size_t ws_size,
                              hipStream_t stream) {
  const float* feat = (const float*)d_in[0];  // [B,N,128]
  const float* A    = (const float*)d_in[1];  // [B,N,N]
  const float* W    = (const float*)d_in[2];  // [128,128]
  const float* bias = (const float*)d_in[3];  // [128]
  float* out = (float*)d_out;                 // [B,N,128]

  const int featN = in_sizes[0];      // B*N*128
  const int aN    = in_sizes[1];      // B*N*N
  const int BN    = featN / 128;      // B*N
  const int N     = aN / BN;
  const int Bb    = BN / N;

  short* wt = (short*)d_ws;           // [128][128] bf16 (32 KB)
  short* ht = wt + 128 * 128;         // [B][128][N] bf16

  hipLaunchKernelGGL(k0_wt, dim3(8), dim3(256), 0, stream, W, wt);
  hipLaunchKernelGGL(k1_feat_x_w, dim3(N / 64, Bb), dim3(256), 0, stream, feat, wt, ht, N);
  hipLaunchKernelGGL(k2_a_x_h, dim3(N / 64, Bb), dim3(256), 0, stream, A, ht, bias, out, N);
}